// Round 1
// 460.791 us; speedup vs baseline: 1.0415x; 1.0415x over previous
//
#include <hip/hip_runtime.h>
#include <hip/hip_bf16.h>

#define RANK   200
#define N_ENT  200000
#define N_REL  500
#define NNZ    500000
#define NB_WIN 256          // blocks in winner stage-1
#define WB_PAD 512          // padded relation slots per partial row

// ---------------------------------------------------------------------------
// Winner semantics (numpy scatter-SET, last write wins):
//   grad_a[subj] = g_a  (pass 1)   then   grad_a[obj] = g_c  (pass 2 overwrites)
// Key encoding for wA: subj write at nnz i -> i ; obj write -> NNZ+i.
// wB winner = max nnz index per relation.
// wB has only 500 ints -> global atomics serialize; per-block LDS max +
// plain-store partials, then a tiny reduce kernel.
// ---------------------------------------------------------------------------
__global__ void winner_kernel(const int* __restrict__ coo,
                              int* __restrict__ wA,
                              int* __restrict__ partial_wB) {
    __shared__ int lwB[WB_PAD];
    for (int t = threadIdx.x; t < WB_PAD; t += blockDim.x) lwB[t] = -1;
    __syncthreads();

    int gtid   = blockIdx.x * blockDim.x + threadIdx.x;
    int stride = gridDim.x * blockDim.x;
    for (int i = gtid; i < NNZ; i += stride) {
        int s = coo[3 * i + 0];
        int r = coo[3 * i + 1];
        int o = coo[3 * i + 2];
        atomicMax(&wA[s], i);           // light contention: ~5 per address
        atomicMax(&wA[o], NNZ + i);
        atomicMax(&lwB[r], i);          // LDS atomic, per-CU
    }
    __syncthreads();
    int* out = partial_wB + (size_t)blockIdx.x * WB_PAD;
    for (int t = threadIdx.x; t < WB_PAD; t += blockDim.x) out[t] = lwB[t];
}

__global__ void wb_reduce_kernel(const int* __restrict__ partial_wB,
                                 int* __restrict__ wB) {
    int t = threadIdx.x;                // single block of WB_PAD threads
    int m = -1;
    for (int nb = 0; nb < NB_WIN; ++nb)
        m = max(m, partial_wB[(size_t)nb * WB_PAD + t]);
    if (t < N_REL) wB[t] = m;
}

// ---------------------------------------------------------------------------
// Fused loss+grad: one 64-lane wave per nnz. Lanes 0-49 load one float4 from
// each of the 3 rows (800 B/row, one transaction each). Butterfly shfl_xor
// reduce leaves the full dot product in EVERY lane, so the gradient operands
// (x=a0, y=b1, z=a2) and d are live in registers. If this nnz is the winner
// for its subj/obj/rel row (exact key match -> unique writer, race-free),
// the wave writes that grad row directly — no second gather pass, no diff
// array, no per-row grad dispatch.
// ---------------------------------------------------------------------------
__global__ void fused_kernel(const int* __restrict__ coo,
                             const float* __restrict__ vals,
                             const float* __restrict__ a,
                             const float* __restrict__ b,
                             const int* __restrict__ wA,
                             const int* __restrict__ wB,
                             float* __restrict__ loss,
                             float* __restrict__ grad_a,
                             float* __restrict__ grad_b) {
    int wave = (blockIdx.x * blockDim.x + threadIdx.x) >> 6;
    int lane = threadIdx.x & 63;
    if (wave >= NNZ) return;
    int s = coo[3 * wave + 0];
    int r = coo[3 * wave + 1];
    int o = coo[3 * wave + 2];
    // winner lookups issued early (broadcast loads, overlap the row gathers)
    int ks = wA[s];
    int ko = wA[o];
    int kr = wB[r];

    float4 x = make_float4(0.f, 0.f, 0.f, 0.f);
    float4 y = x, z = x;
    float sum = 0.0f;
    if (lane < RANK / 4) {
        x = ((const float4*)(a + (size_t)s * RANK))[lane];
        y = ((const float4*)(b + (size_t)r * RANK))[lane];
        z = ((const float4*)(a + (size_t)o * RANK))[lane];
        sum = x.x * y.x * z.x + x.y * y.y * z.y
            + x.z * y.z * z.z + x.w * y.w * z.w;
    }
    #pragma unroll
    for (int off = 32; off > 0; off >>= 1)
        sum += __shfl_xor(sum, off, 64);        // every lane gets the total

    float d = sum - vals[wave];
    if (lane == 0) loss[wave] = d * d;
    float d2 = 2.0f * d;

    if (lane < RANK / 4) {
        if (ks == wave) {                       // g_a = d2 * b1 * a2
            float4* outp = (float4*)(grad_a + (size_t)s * RANK);
            outp[lane] = make_float4(d2 * y.x * z.x, d2 * y.y * z.y,
                                     d2 * y.z * z.z, d2 * y.w * z.w);
        }
        if (ko == NNZ + wave) {                 // g_c = d2 * a0 * b1
            float4* outp = (float4*)(grad_a + (size_t)o * RANK);
            outp[lane] = make_float4(d2 * x.x * y.x, d2 * x.y * y.y,
                                     d2 * x.z * y.z, d2 * x.w * y.w);
        }
        if (kr == wave) {                       // g_b = d2 * a0 * a2
            float4* outp = (float4*)(grad_b + (size_t)r * RANK);
            outp[lane] = make_float4(d2 * x.x * z.x, d2 * x.y * z.y,
                                     d2 * x.z * z.z, d2 * x.w * z.w);
        }
    }
}

// ---------------------------------------------------------------------------
// Zero-fill for untouched rows (~e^-5 of entities ~ 1350 rows + rare rels).
// Thread-per-row check, ballot-compact within the wave, whole wave zeroes
// each flagged row (coalesced 800 B store).
// ---------------------------------------------------------------------------
__global__ void zero_untouched_kernel(const int* __restrict__ wA,
                                      const int* __restrict__ wB,
                                      float* __restrict__ grad_a,
                                      float* __restrict__ grad_b) {
    int tid  = blockIdx.x * blockDim.x + threadIdx.x;
    int lane = threadIdx.x & 63;
    bool need = false;
    if (tid < N_ENT) {
        need = (wA[tid] < 0);
    } else if (tid < N_ENT + N_REL) {
        need = (wB[tid - N_ENT] < 0);
    }
    unsigned long long mask = __ballot(need);
    while (mask) {
        int src = __ffsll((long long)mask) - 1;
        mask &= mask - 1;
        int rowsel = __shfl(tid, src, 64);
        float4* outp = (rowsel < N_ENT)
            ? (float4*)(grad_a + (size_t)rowsel * RANK)
            : (float4*)(grad_b + (size_t)(rowsel - N_ENT) * RANK);
        if (lane < RANK / 4)
            outp[lane] = make_float4(0.f, 0.f, 0.f, 0.f);
    }
}

extern "C" void kernel_launch(void* const* d_in, const int* in_sizes, int n_in,
                              void* d_out, int out_size, void* d_ws, size_t ws_size,
                              hipStream_t stream) {
    const int*   coo  = (const int*)d_in[0];    // (NNZ, 3) int32
    const float* vals = (const float*)d_in[1];  // (NNZ,)   fp32
    const float* a    = (const float*)d_in[2];  // (N_ENT, RANK)
    const float* b    = (const float*)d_in[3];  // (N_REL, RANK)

    float* loss   = (float*)d_out;                       // NNZ
    float* grad_a = loss + NNZ;                          // N_ENT*RANK
    float* grad_b = grad_a + (size_t)N_ENT * RANK;       // N_REL*RANK

    int* wA         = (int*)d_ws;                        // N_ENT ints
    int* wB         = wA + N_ENT;                        // WB_PAD ints
    int* partial_wB = wB + WB_PAD;                       // NB_WIN*WB_PAD ints

    // wA init to -1 (0xFF bytes); wB / partial_wB are fully overwritten.
    hipMemsetAsync(wA, 0xFF, (size_t)N_ENT * sizeof(int), stream);

    winner_kernel<<<NB_WIN, 256, 0, stream>>>(coo, wA, partial_wB);
    wb_reduce_kernel<<<1, WB_PAD, 0, stream>>>(partial_wB, wB);
    {
        long long total = (long long)NNZ * 64;
        int threads = 256;
        long long blocks = (total + threads - 1) / threads;
        fused_kernel<<<(int)blocks, threads, 0, stream>>>(coo, vals, a, b, wA, wB,
                                                          loss, grad_a, grad_b);
    }
    {
        int total   = N_ENT + N_REL;
        int threads = 256;
        int blocks  = (total + threads - 1) / threads;
        zero_untouched_kernel<<<blocks, threads, 0, stream>>>(wA, wB, grad_a, grad_b);
    }
}

// Round 5
// 439.490 us; speedup vs baseline: 1.0920x; 1.0485x over previous
//
#include <hip/hip_runtime.h>
#include <hip/hip_bf16.h>

#define RANK   200
#define N_ENT  200000
#define N_REL  500
#define NNZ    500000
#define NB_WIN 256          // blocks in winner stage-1
#define WB_PAD 512          // padded relation slots per partial row

// Native 4-float vector: __builtin_nontemporal_store requires a native
// vector type, not HIP's float4 class (compile error otherwise).
typedef float f32x4 __attribute__((ext_vector_type(4)));

__device__ __forceinline__ void nt_store4(float* p,
                                          float a, float b_, float c, float d) {
    f32x4 v = {a, b_, c, d};
    __builtin_nontemporal_store(v, (f32x4*)p);
}

// ---------------------------------------------------------------------------
// Winner semantics (numpy scatter-SET, last write wins):
//   grad_a[subj] = g_a  (pass 1)   then   grad_a[obj] = g_c  (pass 2 overwrites)
// Key encoding for wA: subj write at nnz i -> i ; obj write -> NNZ+i.
// wB winner = max nnz index per relation.
// wB has only 500 ints -> global atomics serialize; per-block LDS max +
// plain-store partials, then a tiny reduce kernel.
// ---------------------------------------------------------------------------
__global__ void winner_kernel(const int* __restrict__ coo,
                              int* __restrict__ wA,
                              int* __restrict__ partial_wB) {
    __shared__ int lwB[WB_PAD];
    for (int t = threadIdx.x; t < WB_PAD; t += blockDim.x) lwB[t] = -1;
    __syncthreads();

    int gtid   = blockIdx.x * blockDim.x + threadIdx.x;
    int stride = gridDim.x * blockDim.x;
    for (int i = gtid; i < NNZ; i += stride) {
        int s = coo[3 * i + 0];
        int r = coo[3 * i + 1];
        int o = coo[3 * i + 2];
        atomicMax(&wA[s], i);           // light contention: ~5 per address
        atomicMax(&wA[o], NNZ + i);
        atomicMax(&lwB[r], i);          // LDS atomic, per-CU
    }
    __syncthreads();
    int* out = partial_wB + (size_t)blockIdx.x * WB_PAD;
    for (int t = threadIdx.x; t < WB_PAD; t += blockDim.x) out[t] = lwB[t];
}

__global__ void wb_reduce_kernel(const int* __restrict__ partial_wB,
                                 int* __restrict__ wB) {
    int t = threadIdx.x;                // single block of WB_PAD threads
    int m = -1;
    for (int nb = 0; nb < NB_WIN; ++nb)
        m = max(m, partial_wB[(size_t)nb * WB_PAD + t]);
    if (t < N_REL) wB[t] = m;
}

// ---------------------------------------------------------------------------
// Fused loss+grad: one 64-lane wave per nnz. Lanes 0-49 load one float4 from
// each of the 3 rows (800 B/row). Butterfly shfl_xor reduce leaves the dot
// product in EVERY lane, so gradient operands (x=a0, y=b1, z=a2) and d stay
// live in registers. Winner-keyed rows are written directly — no second
// gather pass, no diff array.
// Output stores are non-temporal: grad/loss bytes are written once and never
// re-read; letting them allocate in the 256 MB LLC evicts `a` (160 MB,
// otherwise fully LLC-resident) — suspected cause of FETCH_SIZE=495 MB.
// ---------------------------------------------------------------------------
__global__ void fused_kernel(const int* __restrict__ coo,
                             const float* __restrict__ vals,
                             const float* __restrict__ a,
                             const float* __restrict__ b,
                             const int* __restrict__ wA,
                             const int* __restrict__ wB,
                             float* __restrict__ loss,
                             float* __restrict__ grad_a,
                             float* __restrict__ grad_b) {
    int wave = (blockIdx.x * blockDim.x + threadIdx.x) >> 6;
    int lane = threadIdx.x & 63;
    if (wave >= NNZ) return;
    int s = coo[3 * wave + 0];
    int r = coo[3 * wave + 1];
    int o = coo[3 * wave + 2];
    // winner lookups issued early (broadcast loads, overlap the row gathers)
    int ks = wA[s];
    int ko = wA[o];
    int kr = wB[r];

    float4 x = make_float4(0.f, 0.f, 0.f, 0.f);
    float4 y = x, z = x;
    float sum = 0.0f;
    if (lane < RANK / 4) {
        x = ((const float4*)(a + (size_t)s * RANK))[lane];
        y = ((const float4*)(b + (size_t)r * RANK))[lane];
        z = ((const float4*)(a + (size_t)o * RANK))[lane];
        sum = x.x * y.x * z.x + x.y * y.y * z.y
            + x.z * y.z * z.z + x.w * y.w * z.w;
    }
    #pragma unroll
    for (int off = 32; off > 0; off >>= 1)
        sum += __shfl_xor(sum, off, 64);        // every lane gets the total

    float d = sum - vals[wave];
    if (lane == 0) __builtin_nontemporal_store(d * d, &loss[wave]);
    float d2 = 2.0f * d;

    if (lane < RANK / 4) {
        if (ks == wave) {                       // g_a = d2 * b1 * a2
            float* outp = grad_a + (size_t)s * RANK + lane * 4;
            nt_store4(outp, d2 * y.x * z.x, d2 * y.y * z.y,
                            d2 * y.z * z.z, d2 * y.w * z.w);
        }
        if (ko == NNZ + wave) {                 // g_c = d2 * a0 * b1
            float* outp = grad_a + (size_t)o * RANK + lane * 4;
            nt_store4(outp, d2 * x.x * y.x, d2 * x.y * y.y,
                            d2 * x.z * y.z, d2 * x.w * y.w);
        }
        if (kr == wave) {                       // g_b = d2 * a0 * a2
            float* outp = grad_b + (size_t)r * RANK + lane * 4;
            nt_store4(outp, d2 * x.x * z.x, d2 * x.y * z.y,
                            d2 * x.z * z.z, d2 * x.w * z.w);
        }
    }
}

// ---------------------------------------------------------------------------
// Zero-fill for untouched rows (~e^-5 of entities ~ 1350 rows + rare rels).
// Thread-per-row check, ballot-compact within the wave, whole wave zeroes
// each flagged row (coalesced 800 B store, non-temporal).
// ---------------------------------------------------------------------------
__global__ void zero_untouched_kernel(const int* __restrict__ wA,
                                      const int* __restrict__ wB,
                                      float* __restrict__ grad_a,
                                      float* __restrict__ grad_b) {
    int tid  = blockIdx.x * blockDim.x + threadIdx.x;
    int lane = threadIdx.x & 63;
    bool need = false;
    if (tid < N_ENT) {
        need = (wA[tid] < 0);
    } else if (tid < N_ENT + N_REL) {
        need = (wB[tid - N_ENT] < 0);
    }
    unsigned long long mask = __ballot(need);
    while (mask) {
        int src = __ffsll((long long)mask) - 1;
        mask &= mask - 1;
        int rowsel = __shfl(tid, src, 64);
        float* outp = (rowsel < N_ENT)
            ? (grad_a + (size_t)rowsel * RANK)
            : (grad_b + (size_t)(rowsel - N_ENT) * RANK);
        if (lane < RANK / 4)
            nt_store4(outp + lane * 4, 0.f, 0.f, 0.f, 0.f);
    }
}

extern "C" void kernel_launch(void* const* d_in, const int* in_sizes, int n_in,
                              void* d_out, int out_size, void* d_ws, size_t ws_size,
                              hipStream_t stream) {
    const int*   coo  = (const int*)d_in[0];    // (NNZ, 3) int32
    const float* vals = (const float*)d_in[1];  // (NNZ,)   fp32
    const float* a    = (const float*)d_in[2];  // (N_ENT, RANK)
    const float* b    = (const float*)d_in[3];  // (N_REL, RANK)

    float* loss   = (float*)d_out;                       // NNZ
    float* grad_a = loss + NNZ;                          // N_ENT*RANK
    float* grad_b = grad_a + (size_t)N_ENT * RANK;       // N_REL*RANK

    int* wA         = (int*)d_ws;                        // N_ENT ints
    int* wB         = wA + N_ENT;                        // WB_PAD ints
    int* partial_wB = wB + WB_PAD;                       // NB_WIN*WB_PAD ints

    // wA init to -1 (0xFF bytes); wB / partial_wB are fully overwritten.
    (void)hipMemsetAsync(wA, 0xFF, (size_t)N_ENT * sizeof(int), stream);

    winner_kernel<<<NB_WIN, 256, 0, stream>>>(coo, wA, partial_wB);
    wb_reduce_kernel<<<1, WB_PAD, 0, stream>>>(partial_wB, wB);
    {
        long long total = (long long)NNZ * 64;
        int threads = 256;
        long long blocks = (total + threads - 1) / threads;
        fused_kernel<<<(int)blocks, threads, 0, stream>>>(coo, vals, a, b, wA, wB,
                                                          loss, grad_a, grad_b);
    }
    {
        int total   = N_ENT + N_REL;
        int threads = 256;
        int blocks  = (total + threads - 1) / threads;
        zero_untouched_kernel<<<blocks, threads, 0, stream>>>(wA, wB, grad_a, grad_b);
    }
}